// Round 6
// baseline (329.117 us; speedup 1.0000x reference)
//
#include <hip/hip_runtime.h>
#include <hip/hip_bf16.h>

// CognitiveWorkspace — single kernel, two block roles.
// Blocks 0..1023 (gate blocks, 16 tokens each):
//   ph1: mean_tag -> gin[tok][64..127]            (LDS)
//   ph2: query = H*Wq^T (bf16 MFMA, K=2048) -> gin[tok][0..63]
//   ph3: gate = sigmoid(gin*Wg^T + bg) (bf16 MFMA, K=128)
//        -> gate_out; out_hub = S_hub*gate + w_hub_shared (from registers)
// Blocks 1024..4095 (stream blocks): grid-stride copy of the non-hub
//   6144 floats/row of S -> out with spoke/priv/tag adds.
// Single writer per output element; no inter-block dependencies.

#define DM 2048      // d_model
#define DSZ 6656     // D_S
#define HUBOFF 4608  // hub_shared offset (floats)
#define TAGOFF 5120
#define NTOK 16384   // B*T
#define DHS 512      // d_hub_shared
#define NGATE 1024   // gate blocks
#define NSTRM 3072   // stream blocks

typedef __attribute__((ext_vector_type(8))) short bf16x8;
typedef __attribute__((ext_vector_type(4))) float f32x4;

__device__ __forceinline__ float sigmoidf_(float x) {
  return 1.0f / (1.0f + __expf(-x));
}
__device__ __forceinline__ short f2bf(float x) {
  return (short)__bfloat16_as_ushort(__float2bfloat16(x));
}
__device__ __forceinline__ bf16x8 load_bf8(const float* p) {
  float4 a = *reinterpret_cast<const float4*>(p);
  float4 b = *reinterpret_cast<const float4*>(p + 4);
  bf16x8 r;
  r[0] = f2bf(a.x); r[1] = f2bf(a.y); r[2] = f2bf(a.z); r[3] = f2bf(a.w);
  r[4] = f2bf(b.x); r[5] = f2bf(b.y); r[6] = f2bf(b.z); r[7] = f2bf(b.w);
  return r;
}

// MFMA 16x16x32 bf16 layouts (m89-verified): A/B: row(col)=lane&15,
// k=(lane>>4)*8+e;  C/D: col=lane&15, row=(lane>>4)*4+reg.
__global__ __launch_bounds__(256) void cw_fused_kernel(
    const float* __restrict__ S, const float* __restrict__ H,
    const float* __restrict__ Wq, const float* __restrict__ Wg,
    const float* __restrict__ bg, const float* __restrict__ whs,
    const float* __restrict__ w_spoke, const float* __restrict__ w_hub_priv,
    const float* __restrict__ tg, const int* __restrict__ lip,
    float* __restrict__ outS, float* __restrict__ gate_out)
{
  __shared__ float gin[16][132];   // stride 132 -> 2-way bank alias (free)

  const int tid = threadIdx.x;
  const int li = *lip;

  if (blockIdx.x < NGATE) {
    // ================= gate block: 16 tokens =================
    const int start = (li > 8) ? (li - 8) : 0;
    const int ntags = li - start;
    const float tscale = (ntags > 0) ? (1.0f / (float)ntags) : 0.0f;
    const int trs = TAGOFF + start * 64;
    const int tok0 = blockIdx.x * 16;

    // ---- ph1: mean over past tags
#pragma unroll
    for (int r = 0; r < 4; ++r) {
      int o = r * 256 + tid;        // 16 tok x 64 d
      int tk = o >> 6, d = o & 63;
      const float* sp = S + (size_t)(tok0 + tk) * DSZ + trs + d;
      float acc = 0.f;
      for (int g = 0; g < ntags; ++g) acc += sp[g * 64];
      gin[tk][64 + d] = acc * tscale;
    }

    const int w = tid >> 6;
    const int l = tid & 63;
    const int l15 = l & 15, l4 = l >> 4;

    // ---- ph2: query = H * Wq^T; wave w owns q-tile w (16 q's)
    {
      const int q0 = w * 16;
      const float* ha = H + (size_t)(tok0 + l15) * DM + l4 * 8;
      const float* wq = Wq + (size_t)(q0 + l15) * DM + l4 * 8;
      f32x4 acc = {0.f, 0.f, 0.f, 0.f};
#pragma unroll 4
      for (int ks = 0; ks < 64; ++ks) {
        bf16x8 af = load_bf8(ha + ks * 32);   // shared across waves (L1)
        bf16x8 bf = load_bf8(wq + ks * 32);
        acc = __builtin_amdgcn_mfma_f32_16x16x32_bf16(af, bf, acc, 0, 0, 0);
      }
#pragma unroll
      for (int i = 0; i < 4; ++i)
        gin[l4 * 4 + i][q0 + l15] = acc[i];
    }
    __syncthreads();

    // ---- ph3: gate = sigmoid(gin * Wg^T + bg); hub epilogue
    bf16x8 afr[4];
#pragma unroll
    for (int ks = 0; ks < 4; ++ks)
      afr[ks] = load_bf8(&gin[l15][ks * 32 + l4 * 8]);

    const float* wgb = Wg + (size_t)l15 * 128 + l4 * 8;
#pragma unroll
    for (int j = 0; j < 8; ++j) {
      const int ht = w * 8 + j;                  // h-tile 0..31
      const float* wgp = wgb + (size_t)ht * 16 * 128;
      f32x4 acc = {0.f, 0.f, 0.f, 0.f};
#pragma unroll
      for (int ks = 0; ks < 4; ++ks) {
        bf16x8 bf = load_bf8(wgp + ks * 32);
        acc = __builtin_amdgcn_mfma_f32_16x16x32_bf16(afr[ks], bf, acc, 0, 0, 0);
      }
      const int h = ht * 16 + l15;
      const float bgv = bg[h];
#pragma unroll
      for (int i = 0; i < 4; ++i) {
        int tok = tok0 + l4 * 4 + i;
        float g = sigmoidf_(acc[i] + bgv);
        gate_out[(size_t)tok * DHS + h] = g;
        size_t so = (size_t)tok * DSZ + HUBOFF + h;
        outS[so] = S[so] * g + whs[(size_t)tok * DHS + h];
      }
    }
  } else {
    // ================= stream block: non-hub quads =================
    const unsigned sp0 = (unsigned)(li * 32), sp1 = sp0 + 32u;          // spoke
    const unsigned hp0 = 768u + (unsigned)(li * 16), hp1 = hp0 + 16u;   // hub_priv
    const unsigned tg0 = 1280u + (unsigned)(li * 16), tg1 = tg0 + 16u;  // tag
    const unsigned rowq = 1536u;
    const unsigned total = (unsigned)NTOK * rowq;   // 25165824

    const float4* S4 = reinterpret_cast<const float4*>(S);
    const float4* SP4 = reinterpret_cast<const float4*>(w_spoke);
    const float4* HP4 = reinterpret_cast<const float4*>(w_hub_priv);
    const float4* TG4 = reinterpret_cast<const float4*>(tg);
    float4* O4 = reinterpret_cast<float4*>(outS);

    for (unsigned i = (blockIdx.x - NGATE) * 256u + tid; i < total;
         i += (unsigned)NSTRM * 256u) {
      unsigned tok = i / rowq;            // magic-multiply
      unsigned c = i - tok * rowq;
      unsigned cp = c + ((c >= 1152u) ? 128u : 0u);   // skip hub quads
      size_t idx = (size_t)tok * 1664u + cp;
      float4 s = S4[idx];
      float4 o = s;
      if (cp >= sp0 && cp < sp1) {
        float4 v = SP4[(size_t)tok * 32u + (cp - sp0)];
        o.x += v.x; o.y += v.y; o.z += v.z; o.w += v.w;
      } else if (cp >= hp0 && cp < hp1) {
        float4 v = HP4[(size_t)tok * 16u + (cp - hp0)];
        o.x += v.x; o.y += v.y; o.z += v.z; o.w += v.w;
      } else if (cp >= tg0 && cp < tg1) {
        float4 v = TG4[(size_t)tok * 16u + (cp - tg0)];
        o.x += v.x; o.y += v.y; o.z += v.z; o.w += v.w;
      }
      O4[idx] = o;
    }
  }
}

extern "C" void kernel_launch(void* const* d_in, const int* in_sizes, int n_in,
                              void* d_out, int out_size, void* d_ws, size_t ws_size,
                              hipStream_t stream) {
  (void)in_sizes; (void)n_in; (void)out_size; (void)d_ws; (void)ws_size;
  const float* S            = (const float*)d_in[0];
  const float* H            = (const float*)d_in[1];
  const float* w_spoke      = (const float*)d_in[2];
  const float* w_hub_priv   = (const float*)d_in[3];
  const float* w_hub_shared = (const float*)d_in[4];
  const float* tg           = (const float*)d_in[5];
  const float* Wq           = (const float*)d_in[6];
  const float* Wg           = (const float*)d_in[7];
  const float* bg           = (const float*)d_in[8];
  const int*   lip          = (const int*)d_in[9];

  float* outS = (float*)d_out;
  float* gate_out = outS + (size_t)NTOK * DSZ;

  cw_fused_kernel<<<NGATE + NSTRM, 256, 0, stream>>>(
      S, H, Wq, Wg, bg, w_hub_shared, w_spoke, w_hub_priv, tg, lip,
      outS, gate_out);
}